// Round 8
// baseline (106.551 us; speedup 1.0000x reference)
//
#include <hip/hip_runtime.h>

#define BATCH 4
#define NPTS  2048
#define DZDIM 128
#define GD    128
#define M_TOT (GD*GD)
#define NTIL  66        // k-tiles per batch: 2112/32 (64 data tiles + 2 zeroed pad tiles)
#define ZP    2112      // xs row pitch (elements); 2048 data + 64 pad
#define WBIN  15        // +-15 bins: covers |x-gx| < 15.5*step (w < 7e-6 outside)

typedef __attribute__((ext_vector_type(8))) __bf16 bf16x8;
typedef __attribute__((ext_vector_type(4))) float floatx4;

__device__ __forceinline__ unsigned int f2bf_bits(float x){
  unsigned int u = __float_as_uint(x);
  u += 0x7FFFu + ((u >> 16) & 1u);
  return u >> 16;
}
__device__ __forceinline__ int point_bin(float px){
  int bin = __float2int_rn((px + 2.0f) * (127.0f / 4.0f));
  return min(GD - 1, max(0, bin));
}

// ---- D1: per-batch hist + scan + atomic-rank scatter (blocks 0..3) | x_grid bcast ----
__global__ __launch_bounds__(256) void prep_kernel(
    const float* __restrict__ x, const float* __restrict__ grid,
    float* __restrict__ out, int* __restrict__ binStart,
    float2* __restrict__ xs, int* __restrict__ perm)
{
  const int tid = threadIdx.x;
  if (blockIdx.x < BATCH){
    __shared__ int h[GD];
    __shared__ int s[GD + 1];
    const int b = blockIdx.x;
    const float2* __restrict__ x2 = (const float2*)x;
    if (tid < GD) h[tid] = 0;
    __syncthreads();
    float2 xv[8]; int bn[8];
#pragma unroll
    for (int u = 0; u < 8; ++u){
      xv[u] = x2[b*NPTS + u*256 + tid];
      bn[u] = point_bin(xv[u].x);
      atomicAdd(&h[bn[u]], 1);
    }
    __syncthreads();
    if (tid == 0){
      int acc = 0;
#pragma unroll
      for (int j = 0; j < GD; ++j){ s[j] = acc; acc += h[j]; }
      s[GD] = acc;
    }
    __syncthreads();
    if (tid <= GD) binStart[b*(GD+1) + tid] = s[tid];
    if (tid < GD) h[tid] = 0;          // reuse as per-bin rank counters
    __syncthreads();
#pragma unroll
    for (int u = 0; u < 8; ++u){
      int j = s[bn[u]] + atomicAdd(&h[bn[u]], 1);   // order in bin arbitrary: sums commute
      xs[(long)b*ZP + j]       = xv[u];
      perm[b*NPTS + j]         = u*256 + tid;
    }
  } else {
    int idx = (blockIdx.x - BATCH) * 256 + tid;   // 0..32767 == GD*GD*2
    float g = grid[idx];
#pragma unroll
    for (int bb = 0; bb < BATCH; ++bb) out[bb*(GD*GD*2) + idx] = g;
  }
}

// ---- D2: zt2[b][t][dz][k] = bf16(z[b][perm[t*32+k]][dz]) : MFMA-B-fragment order ----
// k fastest (32 per tile) -> a wave's B-frag load is one contiguous 1KB block.
// Pad tiles t=64,65 zeroed (MFMA never reads poison).
__global__ __launch_bounds__(256) void ztbuild_kernel(
    const float* __restrict__ z, const int* __restrict__ perm,
    unsigned short* __restrict__ zt2)
{
  const int b   = blockIdx.y;
  const int t   = blockIdx.x;                // 0..65
  const int jj  = threadIdx.x & 31;          // k within tile
  const int oct = threadIdx.x >> 5;          // 0..7
  unsigned short* __restrict__ tb = zt2 + ((long)b*NTIL + t) * (DZDIM*32);
  if (t >= 64){
#pragma unroll
    for (int r = 0; r < 4; ++r){
      int c = oct*4 + r;
      long base = (long)(4*c)*32 + jj;
      tb[base] = 0; tb[base+32] = 0; tb[base+64] = 0; tb[base+96] = 0;
    }
    return;
  }
  const int j = t*32 + jj;
  const int n = perm[b*NPTS + j];
  const float4* __restrict__ z4 = (const float4*)z;
  const long rb = (long)(b*NPTS + n) * 32;
#pragma unroll
  for (int r = 0; r < 4; ++r){
    int c = oct*4 + r;                       // float4 index 0..31 -> dz = 4c..4c+3
    float4 v = z4[rb + c];
    long base = (long)(4*c)*32 + jj;         // rows dz=4c..4c+3, col k=jj
    tb[base     ] = (unsigned short)f2bf_bits(v.x);
    tb[base + 32] = (unsigned short)f2bf_bits(v.y);
    tb[base + 64] = (unsigned short)f2bf_bits(v.z);
    tb[base + 96] = (unsigned short)f2bf_bits(v.w);
  }
}

// ---- D3: main. B-frags read DIRECTLY from L1/L2 (fragment-ordered zt2) — no Zlds,
//      no global_load_lds, no per-step barriers. XS window staged to LDS once. ----
__global__ __launch_bounds__(256, 2) void setconv_mfma_kernel(
    const float2* __restrict__ xs, const int* __restrict__ binStart,
    const unsigned short* __restrict__ zt2, const float* __restrict__ lsp,
    float* __restrict__ outz)
{
  __shared__ __align__(16) float2 XSL[ZP];   // worst-case window: 16.9 KB

  const int tid = threadIdx.x, lane = tid & 63, wv = tid >> 6;
  const int bid = blockIdx.x;
  const int g   = bid & 7;                   // XCD pin -> 16-row band (L2 locality)
  const int s   = bid >> 3;
  const int b   = s & 3;
  const int il  = s >> 2;                    // 0..15
  const int i   = g*16 + il;                 // grid row (gx index)

  const float l0 = 1e-5f + log1pf(expf(lsp[0]));
  const float l1 = 1e-5f + log1pf(expf(lsp[1]));
  const float LOG2E = 1.4426950408889634f;
  const float c0 = -0.5f * LOG2E / (l0*l0);
  const float c1 = -0.5f * LOG2E / (l1*l1);
  const float step = 4.0f / 127.0f;
  const float gx   = -2.0f + (float)i * step;

  const int lo   = binStart[b*(GD+1) + max(0, i - WBIN)];
  const int hi   = binStart[b*(GD+1) + min(GD-1, i + WBIN) + 1];
  const int lo32 = lo & ~31;                 // tile-align k-base (extra pts get true tiny w)
  const int len  = hi - lo32;
  const int T    = (len + 31) / 32;

  // one-time XS window stage (reads stay inside the ZP-padded row)
  for (int u = tid; u < T*32; u += 256)
    XSL[u] = xs[(long)b*ZP + lo32 + u];
  __syncthreads();

  const int q  = lane >> 4;
  const int ml = lane & 15;
  const float gy0 = -2.0f + (float)(wv*16 + ml) * step;  // A-frag row (m) of this lane
  const float gy1 = gy0 + 64.0f * step;                  // second A-frag: m + 64

  // per-lane byte offset inside a 128x32 tile: row tz*16+ml, cols q*8..+8
  const unsigned short* __restrict__ ztb =
      zt2 + ((long)b*NTIL + (lo32 >> 5)) * (DZDIM*32) + ml*32 + q*8;

  floatx4 acc[2][8];
#pragma unroll
  for (int hh = 0; hh < 2; ++hh)
#pragma unroll
    for (int tz = 0; tz < 8; ++tz) acc[hh][tz] = (floatx4){0.f, 0.f, 0.f, 0.f};

  for (int t = 0; t < T; ++t){
    const unsigned short* __restrict__ tb = ztb + (long)t*(DZDIM*32);
    // issue all 8 B-frag loads (each wave-instr = 1KB contiguous, L1/L2-hot)
    bf16x8 bfr[8];
#pragma unroll
    for (int tz = 0; tz < 8; ++tz)
      bfr[tz] = *(const bf16x8*)&tb[tz*16*32];
    // A-frags in-register while loads are in flight; pack every 2 k-slots (VGPR cap)
    const int kb = t*32 + q*8;
    union { unsigned int u[4]; bf16x8 v; } A0, A1;
#pragma unroll
    for (int rr = 0; rr < 4; ++rr){
      float w0a, w0b, w1a, w1b;
#pragma unroll
      for (int h = 0; h < 2; ++h){
        int r = rr*2 + h;
        float2 p = XSL[kb + r];              // 16-lane LDS broadcast
        float dx = gx - p.x;
        float t0 = c0*dx*dx;
        float dy0 = gy0 - p.y, dy1 = gy1 - p.y;
        float a0 = fmaf(c1*dy0, dy0, t0);
        float a1 = fmaf(c1*dy1, dy1, t0);
        bool ok = (kb + r) < len;
        float e0 = ok ? __builtin_amdgcn_exp2f(a0) : 0.f;  // NaN-safe (cndmask)
        float e1 = ok ? __builtin_amdgcn_exp2f(a1) : 0.f;
        if (h == 0){ w0a = e0; w1a = e1; } else { w0b = e0; w1b = e1; }
      }
      asm("v_cvt_pk_bf16_f32 %0, %1, %2" : "=v"(A0.u[rr]) : "v"(w0a), "v"(w0b));
      asm("v_cvt_pk_bf16_f32 %0, %1, %2" : "=v"(A1.u[rr]) : "v"(w1a), "v"(w1b));
    }
    bf16x8 af0 = A0.v, af1 = A1.v;
#pragma unroll
    for (int tz = 0; tz < 8; ++tz){
      acc[0][tz] = __builtin_amdgcn_mfma_f32_16x16x32_bf16(af0, bfr[tz], acc[0][tz], 0, 0, 0);
      acc[1][tz] = __builtin_amdgcn_mfma_f32_16x16x32_bf16(af1, bfr[tz], acc[1][tz], 0, 0, 0);
    }
  }

  // epilogue: C/D col(dz)=ml, row(m)=q*4+r; halves at m and m+64
#pragma unroll
  for (int hh = 0; hh < 2; ++hh){
    const long obase = ((long)(b*M_TOT + i*GD + hh*64 + wv*16 + q*4) << 7) + ml;
#pragma unroll
    for (int tz = 0; tz < 8; ++tz)
#pragma unroll
      for (int r = 0; r < 4; ++r)
        outz[obase + ((long)r << 7) + tz*16] = acc[hh][tz][r];
  }
}

extern "C" void kernel_launch(void* const* d_in, const int* in_sizes, int n_in,
                              void* d_out, int out_size, void* d_ws, size_t ws_size,
                              hipStream_t stream)
{
  const float* x    = (const float*)d_in[0];
  const float* z    = (const float*)d_in[1];
  const float* grid = (const float*)d_in[2];
  const float* lsp  = (const float*)d_in[3];
  float* out = (float*)d_out;

  char* ws = (char*)d_ws;
  int*            binStart = (int*)ws;                        // 4*129*4       = 2064 B
  int*            perm     = (int*)(ws + 2064);               // 4*2048*4      = 32768 B
  float2*         xs       = (float2*)(ws + 34832);           // 4*ZP*8        = 67584 B
  unsigned short* zt2      = (unsigned short*)(ws + 102416);  // 4*66*128*32*2 = 2162688 B

  hipLaunchKernelGGL(prep_kernel, dim3(BATCH + GD), dim3(256), 0, stream,
                     x, grid, out, binStart, xs, perm);
  hipLaunchKernelGGL(ztbuild_kernel, dim3(NTIL, BATCH), dim3(256), 0, stream,
                     z, perm, zt2);
  hipLaunchKernelGGL(setconv_mfma_kernel, dim3(GD*BATCH), dim3(256), 0, stream,
                     xs, binStart, zt2, lsp, out + BATCH*GD*GD*2);
}

// Round 10
// 101.098 us; speedup vs baseline: 1.0539x; 1.0539x over previous
//
#include <hip/hip_runtime.h>

#define BATCH 4
#define NPTS  2048
#define DZDIM 128
#define GD    128
#define M_TOT (GD*GD)
#define TN    64        // k-tile (doubled from r7: half the barriers/stage-issues per k)
#define PZ    72        // Z LDS row pitch (ushorts); 64 data + 8 pad; stride 36 dwords -> 2-way banks (free)
#define ZP    2112      // zt / xs row pitch (elements); 2048 data + 64 pad, 16B-aligned rows
#define WBIN  15        // +-15 bins: covers |x-gx| < 15.5*step (w < 7e-6 outside)

typedef __attribute__((ext_vector_type(8))) __bf16 bf16x8;
typedef __attribute__((ext_vector_type(4))) float floatx4;

__device__ __forceinline__ unsigned int f2bf_bits(float x){
  unsigned int u = __float_as_uint(x);
  u += 0x7FFFu + ((u >> 16) & 1u);
  return u >> 16;
}
__device__ __forceinline__ int point_bin(float px){
  int bin = __float2int_rn((px + 2.0f) * (127.0f / 4.0f));
  return min(GD - 1, max(0, bin));
}

// ---- D1: per-batch hist + scan + atomic-rank scatter (blocks 0..3) | x_grid bcast ----
__global__ __launch_bounds__(256) void prep_kernel(
    const float* __restrict__ x, const float* __restrict__ grid,
    float* __restrict__ out, int* __restrict__ binStart,
    float2* __restrict__ xs, int* __restrict__ perm)
{
  const int tid = threadIdx.x;
  if (blockIdx.x < BATCH){
    __shared__ int h[GD];
    __shared__ int s[GD + 1];
    const int b = blockIdx.x;
    const float2* __restrict__ x2 = (const float2*)x;
    if (tid < GD) h[tid] = 0;
    __syncthreads();
    float2 xv[8]; int bn[8];
#pragma unroll
    for (int u = 0; u < 8; ++u){
      xv[u] = x2[b*NPTS + u*256 + tid];
      bn[u] = point_bin(xv[u].x);
      atomicAdd(&h[bn[u]], 1);
    }
    __syncthreads();
    if (tid == 0){
      int acc = 0;
#pragma unroll
      for (int j = 0; j < GD; ++j){ s[j] = acc; acc += h[j]; }
      s[GD] = acc;
    }
    __syncthreads();
    if (tid <= GD) binStart[b*(GD+1) + tid] = s[tid];
    if (tid < GD) h[tid] = 0;          // reuse as per-bin rank counters
    __syncthreads();
#pragma unroll
    for (int u = 0; u < 8; ++u){
      int j = s[bn[u]] + atomicAdd(&h[bn[u]], 1);   // order in bin arbitrary: sums commute
      xs[(long)b*ZP + j]       = xv[u];
      perm[b*NPTS + j]         = u*256 + tid;
    }
  } else {
    int idx = (blockIdx.x - BATCH) * 256 + tid;   // 0..32767 == GD*GD*2
    float g = grid[idx];
#pragma unroll
    for (int bb = 0; bb < BATCH; ++bb) out[bb*(GD*GD*2) + idx] = g;
  }
}

// ---- D2: zt[b][dz][j] = bf16(z[b][perm[j]][dz]) : sorted, transposed, bf16 ----
__global__ __launch_bounds__(256) void ztbuild_kernel(
    const float* __restrict__ z, const int* __restrict__ perm,
    unsigned short* __restrict__ zt)
{
  const int b   = blockIdx.y;
  const int jj  = threadIdx.x & 31;
  const int oct = threadIdx.x >> 5;          // 0..7
  const int j = blockIdx.x*32 + jj;
  const int n = perm[b*NPTS + j];
  const float4* __restrict__ z4 = (const float4*)z;
  const long rb = (long)(b*NPTS + n) * 32;
#pragma unroll
  for (int r = 0; r < 4; ++r){
    int c = oct*4 + r;                       // float4 index 0..31 -> dz = 4c..4c+3
    float4 v = z4[rb + c];
    long o = ((long)(b*DZDIM + 4*c) * ZP) + j;
    zt[o        ] = (unsigned short)f2bf_bits(v.x);
    zt[o +   ZP ] = (unsigned short)f2bf_bits(v.y);
    zt[o + 2*ZP ] = (unsigned short)f2bf_bits(v.z);
    zt[o + 3*ZP ] = (unsigned short)f2bf_bits(v.w);
  }
}

// ---- D3: main — r7 skeleton (verified) with TN=64: inner body = 2x r7's 32-k body. ----
__global__ __launch_bounds__(256, 2) void setconv_mfma_kernel(
    const float2* __restrict__ xs, const int* __restrict__ binStart,
    const unsigned short* __restrict__ zt, const float* __restrict__ lsp,
    float* __restrict__ outz)
{
  __shared__ __align__(16) unsigned short Zlds[2][DZDIM * PZ];  // 2 x 18432 B
  __shared__ __align__(16) float2 XS[2][TN];                    // 2 x 512 B

  const int tid = threadIdx.x, lane = tid & 63, wv = tid >> 6;
  const int bid = blockIdx.x;
  const int g   = bid & 7;                   // XCD pin -> 16-row band (L2 locality)
  const int s   = bid >> 3;
  const int b   = s & 3;
  const int il  = s >> 2;                    // 0..15
  const int i   = g*16 + il;                 // grid row (gx index)

  const float l0 = 1e-5f + log1pf(expf(lsp[0]));
  const float l1 = 1e-5f + log1pf(expf(lsp[1]));
  const float LOG2E = 1.4426950408889634f;
  const float c0 = -0.5f * LOG2E / (l0*l0);
  const float c1 = -0.5f * LOG2E / (l1*l1);
  const float step = 4.0f / 127.0f;
  const float gx   = -2.0f + (float)i * step;

  const int lo  = binStart[b*(GD+1) + max(0, i - WBIN)];
  const int hi  = binStart[b*(GD+1) + min(GD-1, i + WBIN) + 1];
  const int lo8 = lo & ~7;                   // 16B-align k-base (extra pts get true tiny w)
  const int len = hi - lo8;
  const int T   = (len + TN - 1) / TN;

  // Z glds per-lane setup: 18 wave-instrs cover 128 rows x 9 chunks (8 data + 1 pad) of 16B
  int goff[5];
#pragma unroll
  for (int u = 0; u < 5; ++u){
    int gi = wv + 4*u;
    if (gi < 18){
      int pos = gi*64 + lane;                // 16B-chunk index in LDS buffer
      int d = pos / 9, c = pos % 9;          // dz row, chunk-in-row
      if (c > 7) c = 7;                      // pad chunk: duplicate a valid address
      goff[u] = (b*DZDIM + d) * ZP + c*8;
    } else goff[u] = 0;
  }

  const int q  = lane >> 4;
  const int ml = lane & 15;
  const float gy0 = -2.0f + (float)(wv*16 + ml) * step;  // A-frag row (m) of this lane
  const float gy1 = gy0 + 64.0f * step;                  // second A-frag: m + 64

  floatx4 acc[2][8];
#pragma unroll
  for (int hh = 0; hh < 2; ++hh)
#pragma unroll
    for (int tz = 0; tz < 8; ++tz) acc[hh][tz] = (floatx4){0.f, 0.f, 0.f, 0.f};

  auto stageZ = [&](int buf, int t){
    const int k0 = lo8 + t*TN;
#pragma unroll
    for (int u = 0; u < 5; ++u){
      int gi = wv + 4*u;
      if (gi < 18){
        const unsigned short* gp = zt + goff[u] + k0;
        __builtin_amdgcn_global_load_lds(
            (__attribute__((address_space(1))) void*)gp,
            (__attribute__((address_space(3))) void*)&Zlds[buf][gi*512],
            16, 0, 0);
      }
    }
  };
  auto stageXS = [&](int buf, int t){
    if (tid < TN)
      XS[buf][tid] = xs[(long)b*ZP + lo8 + t*TN + tid];  // pad reads in-bounds (ZP)
  };

  if (T > 0){
    stageZ(0, 0);
    stageXS(0, 0);
    __syncthreads();
    for (int t = 0; t < T; ++t){
      const int cur = t & 1, nxt = 1 - cur;
      if (t + 1 < T){ stageZ(nxt, t + 1); stageXS(nxt, t + 1); }
#pragma unroll
      for (int half = 0; half < 2; ++half){
        // in-register weights: one exp2 per (m,k); k-mask via cndmask (NaN-safe)
        float w0[8], w1[8];
#pragma unroll
        for (int r = 0; r < 8; ++r){
          float2 p = XS[cur][half*32 + q*8 + r];         // 16-lane broadcast read
          float dx = gx - p.x;
          float t0 = c0*dx*dx;
          float dy0 = gy0 - p.y, dy1 = gy1 - p.y;
          float a0 = fmaf(c1*dy0, dy0, t0);
          float a1 = fmaf(c1*dy1, dy1, t0);
          bool ok = (t*TN + half*32 + q*8 + r) < len;
          w0[r] = ok ? __builtin_amdgcn_exp2f(a0) : 0.f;
          w1[r] = ok ? __builtin_amdgcn_exp2f(a1) : 0.f;
        }
        union { unsigned int u[4]; bf16x8 v; } A0, A1;
        asm("v_cvt_pk_bf16_f32 %0, %1, %2" : "=v"(A0.u[0]) : "v"(w0[0]), "v"(w0[1]));
        asm("v_cvt_pk_bf16_f32 %0, %1, %2" : "=v"(A0.u[1]) : "v"(w0[2]), "v"(w0[3]));
        asm("v_cvt_pk_bf16_f32 %0, %1, %2" : "=v"(A0.u[2]) : "v"(w0[4]), "v"(w0[5]));
        asm("v_cvt_pk_bf16_f32 %0, %1, %2" : "=v"(A0.u[3]) : "v"(w0[6]), "v"(w0[7]));
        asm("v_cvt_pk_bf16_f32 %0, %1, %2" : "=v"(A1.u[0]) : "v"(w1[0]), "v"(w1[1]));
        asm("v_cvt_pk_bf16_f32 %0, %1, %2" : "=v"(A1.u[1]) : "v"(w1[2]), "v"(w1[3]));
        asm("v_cvt_pk_bf16_f32 %0, %1, %2" : "=v"(A1.u[2]) : "v"(w1[4]), "v"(w1[5]));
        asm("v_cvt_pk_bf16_f32 %0, %1, %2" : "=v"(A1.u[3]) : "v"(w1[6]), "v"(w1[7]));
        bf16x8 af0 = A0.v, af1 = A1.v;
#pragma unroll
        for (int tz = 0; tz < 8; ++tz){
          bf16x8 bf = *(const bf16x8*)&Zlds[cur][(tz*16 + ml)*PZ + half*32 + q*8];
          acc[0][tz] = __builtin_amdgcn_mfma_f32_16x16x32_bf16(af0, bf, acc[0][tz], 0, 0, 0);
          acc[1][tz] = __builtin_amdgcn_mfma_f32_16x16x32_bf16(af1, bf, acc[1][tz], 0, 0, 0);
        }
      }
      __syncthreads();                     // drains vmcnt (Z glds); single barrier per tile
    }
  }

  // epilogue: C/D col(dz)=ml, row(m)=q*4+r; halves at m and m+64
#pragma unroll
  for (int hh = 0; hh < 2; ++hh){
    const long obase = ((long)(b*M_TOT + i*GD + hh*64 + wv*16 + q*4) << 7) + ml;
#pragma unroll
    for (int tz = 0; tz < 8; ++tz)
#pragma unroll
      for (int r = 0; r < 4; ++r)
        outz[obase + ((long)r << 7) + tz*16] = acc[hh][tz][r];
  }
}

extern "C" void kernel_launch(void* const* d_in, const int* in_sizes, int n_in,
                              void* d_out, int out_size, void* d_ws, size_t ws_size,
                              hipStream_t stream)
{
  const float* x    = (const float*)d_in[0];
  const float* z    = (const float*)d_in[1];
  const float* grid = (const float*)d_in[2];
  const float* lsp  = (const float*)d_in[3];
  float* out = (float*)d_out;

  char* ws = (char*)d_ws;
  int*            binStart = (int*)ws;                        // 4*129*4    = 2064 B
  int*            perm     = (int*)(ws + 2064);               // 4*2048*4   = 32768 B
  float2*         xs       = (float2*)(ws + 34832);           // 4*ZP*8     = 67584 B
  unsigned short* zt       = (unsigned short*)(ws + 102416);  // 4*128*ZP*2 = 2162688 B

  hipLaunchKernelGGL(prep_kernel, dim3(BATCH + GD), dim3(256), 0, stream,
                     x, grid, out, binStart, xs, perm);
  hipLaunchKernelGGL(ztbuild_kernel, dim3(NPTS/32, BATCH), dim3(256), 0, stream,
                     z, perm, zt);
  hipLaunchKernelGGL(setconv_mfma_kernel, dim3(GD*BATCH), dim3(256), 0, stream,
                     xs, binStart, zt, lsp, out + BATCH*GD*GD*2);
}